// Round 7
// baseline (1307.959 us; speedup 1.0000x reference)
//
#include <hip/hip_runtime.h>
#include <hip/hip_bf16.h>
#include <math.h>

#define BS 32
#define QN 256
#define TN 128
#define NCLS 2048
#define NTGT (BS * TN)  // 4096

// ---------------------------------------------------------------------------
// Detect whether agent_mask is stored as 1-byte bools or 4-byte int32.
// ---------------------------------------------------------------------------
__global__ void detect_mask_layout(const unsigned char* __restrict__ m, int* flag) {
    __shared__ int found;
    if (threadIdx.x == 0) found = 0;
    __syncthreads();
    int local = 0;
    for (int i = threadIdx.x; i < BS * QN; i += blockDim.x) {
        if ((i & 3) != 0 && m[i] != 0) local = 1;
    }
    if (local) atomicOr(&found, 1);
    __syncthreads();
    if (threadIdx.x == 0) *flag = found;  // 1 = byte layout, 0 = int32 layout
}

// ---------------------------------------------------------------------------
// C[b,q,jj] = -(softmax(logits[b,q,:])[labels_flat[jj]]), zeroed if masked.
// Also writes the block-diagonal slice transposed into CT[b][i][q] directly
// (replaces the separate transpose kernel).
// ---------------------------------------------------------------------------
__global__ __launch_bounds__(256) void compute_C_kernel(
    const float* __restrict__ logits, const int* __restrict__ labels,
    const unsigned char* __restrict__ mask_b, const int* __restrict__ use_bg,
    const int* __restrict__ layout_flag, float* __restrict__ C,
    float* __restrict__ CT) {
    __shared__ float prob_sh[NCLS];
    __shared__ int lab_sh[NTGT];
    __shared__ float red[4];

    const int tid = threadIdx.x;
    const int bq = blockIdx.x;  // b*QN + q
    const int b = bq >> 8;
    const int q = bq & 255;
    const float* row = logits + (size_t)bq * NCLS;

    for (int k = tid; k < NTGT; k += 256) lab_sh[k] = labels[k];

    float x[8];
    float m = -INFINITY;
#pragma unroll
    for (int k = 0; k < 8; k++) {
        x[k] = row[tid + k * 256];
        m = fmaxf(m, x[k]);
    }
#pragma unroll
    for (int off = 32; off >= 1; off >>= 1) m = fmaxf(m, __shfl_xor(m, off));
    if ((tid & 63) == 0) red[tid >> 6] = m;
    __syncthreads();
    m = fmaxf(fmaxf(red[0], red[1]), fmaxf(red[2], red[3]));
    __syncthreads();

    float e[8];
    float s = 0.f;
#pragma unroll
    for (int k = 0; k < 8; k++) {
        e[k] = expf(x[k] - m);
        s += e[k];
    }
#pragma unroll
    for (int off = 32; off >= 1; off >>= 1) s += __shfl_xor(s, off);
    if ((tid & 63) == 0) red[tid >> 6] = s;
    __syncthreads();
    s = ((red[0] + red[1]) + red[2]) + red[3];

#pragma unroll
    for (int k = 0; k < 8; k++) prob_sh[tid + k * 256] = e[k] / s;

    const int ub = *use_bg;
    int am;
    if (*layout_flag)
        am = mask_b[bq];
    else
        am = ((const int*)mask_b)[bq];
    const bool zero_row = (ub == 0) && (am == 0);
    __syncthreads();

    // packed float4 C writes (coalesced 16 B/lane)
    float4* Crow4 = (float4*)(C + (size_t)bq * NTGT);
#pragma unroll
    for (int k = 0; k < 4; k++) {
        const int idx4 = tid + k * 256;           // float4 index
        const int4 lab4 = *(const int4*)&lab_sh[idx4 * 4];
        float4 out;
        if (zero_row) {
            out = make_float4(0.f, 0.f, 0.f, 0.f);
        } else {
            out.x = -prob_sh[lab4.x];
            out.y = -prob_sh[lab4.y];
            out.z = -prob_sh[lab4.z];
            out.w = -prob_sh[lab4.w];
        }
        Crow4[idx4] = out;
    }

    // block-diagonal transposed slice: CT[b][i][q]
    if (CT && tid < TN) {
        const float val = zero_row ? 0.0f : -prob_sh[lab_sh[b * TN + tid]];
        CT[((size_t)b * TN + tid) * QN + q] = val;
    }
}

// ---------------------------------------------------------------------------
// Cross-lane helpers.
// ---------------------------------------------------------------------------
template <int CTRL>
__device__ __forceinline__ double dpp_mov_f64(double x) {
    union { double d; int i[2]; } a, r;
    a.d = x;
    r.i[0] = __builtin_amdgcn_update_dpp(0, a.i[0], CTRL, 0xF, 0xF, true);
    r.i[1] = __builtin_amdgcn_update_dpp(0, a.i[1], CTRL, 0xF, 0xF, true);
    return r.d;
}
__device__ __forceinline__ double read_lane_f64(double x, int srclane) {
    union { double d; int i[2]; } a, r;
    a.d = x;
    r.i[0] = __builtin_amdgcn_readlane(a.i[0], srclane);
    r.i[1] = __builtin_amdgcn_readlane(a.i[1], srclane);
    return r.d;
}

#define QUAD_XOR1 0xB1   // quad_perm(1,0,3,2)
#define QUAD_XOR2 0x4E   // quad_perm(2,3,0,1)
#define ROW_ROR4  0x124  // row_ror:4
#define ROW_ROR8  0x128  // row_ror:8

// first tied column index from 4 slot-ballots (scalar, wave-uniform)
__device__ __forceinline__ int first_tied(unsigned long long B0, unsigned long long B1,
                                          unsigned long long B2, unsigned long long B3) {
    int jmin = 0x7fffffff;
    if (B0) { const int c = ((__ffsll((long long)B0) - 1) << 2) + 0; jmin = c < jmin ? c : jmin; }
    if (B1) { const int c = ((__ffsll((long long)B1) - 1) << 2) + 1; jmin = c < jmin ? c : jmin; }
    if (B2) { const int c = ((__ffsll((long long)B2) - 1) << 2) + 2; jmin = c < jmin ? c : jmin; }
    if (B3) { const int c = ((__ffsll((long long)B3) - 1) << 2) + 3; jmin = c < jmin ? c : jmin; }
    return jmin;
}

// ---------------------------------------------------------------------------
// Jonker-Volgenant, exact replica of reference _lsa() on the transposed
// problem (nr=TN=128 rows=targets, nc=QN=256 cols=queries). One wave/batch.
// Lane owns cols 4l..4l+3 (d, v, SC, path, row4col in regs) and rows 2l,2l+1
// (u mirror, du, SR, col4row in regs); u write-through to LDS for broadcast.
//
// 2-stage software pipeline, manual unroll-by-2 (bodies alternate register
// sets ccA/uiA <-> ccB/uiB, NO copies): each body's TOP issues the LDS loads
// for the next pop's guessed row (guess = next bit of the tied-set ballot,
// selected at the previous body's tail), a full body (~150 cyc) before the
// consume -> LDS latency hidden on the fast path. Guess is invalidated only
// if the just-scanned row produced an improvement <= current min (then full
// DPP-tree reduce + reload; bit-exact vs scipy's fresh argmin).
// ---------------------------------------------------------------------------
__global__ __launch_bounds__(64) void lsa_kernel(const float* __restrict__ C,
                                                 const float* __restrict__ CT,
                                                 float* __restrict__ rows_out,
                                                 float* __restrict__ cols_out) {
    const int b = blockIdx.x;
    const int lane = threadIdx.x;  // 0..63
    const int j0 = lane * 4;

    __shared__ float cost_sh[TN * QN];  // [i][q], 128 KB
    __shared__ double u_sh[TN];
    __shared__ int col4row_sh[TN];      // epilogue only

    if (CT) {
        const float4* src = (const float4*)(CT + (size_t)b * TN * QN);
        float4* dst = (float4*)cost_sh;
#pragma unroll 8
        for (int it = 0; it < TN * QN / 4 / 64; it++) {
            const int idx = it * 64 + lane;
            dst[idx] = src[idx];
        }
    } else {
        const float* cbsrc = C + (size_t)b * QN * NTGT + b * TN;
        for (int it = 0; it < 512; it++) {
            const int j = it >> 1;
            const int i = lane + 64 * (it & 1);
            cost_sh[i * QN + j] = cbsrc[(size_t)j * NTGT + i];
        }
    }
    u_sh[2 * lane] = 0.0;
    u_sh[2 * lane + 1] = 0.0;
    __syncthreads();

    // persistent per-lane state
    double v0 = 0.0, v1 = 0.0, v2 = 0.0, v3 = 0.0;  // col duals (owned cols)
    double u0 = 0.0, u1 = 0.0;                      // row duals (owned rows)
    int rc0 = -1, rc1 = -1, rc2 = -1, rc3 = -1;     // row4col (owned cols)
    int cr0 = -1, cr1 = -1;                         // col4row (owned rows)

    for (int cur = 0; cur < TN; cur++) {
        double dv0 = INFINITY, dv1 = INFINITY, dv2 = INFINITY, dv3 = INFINITY;
        double duR0 = 0.0, duR1 = 0.0;
        int sc = 0, sr = 0;
        int p0 = 0, p1 = 0, p2 = 0, p3 = 0;
        if (lane == (cur >> 1)) sr = 1 << (cur & 1);  // SR[cur]

        int irow = cur;
        double m_d = 0.0;
        unsigned long long B0 = 0, B1 = 0, B2 = 0, B3 = 0;
        int sink = -1;
        bool have_g = false;
        int jg = 0, krcg = 0;

        // prologue: issue loads for row cur into set A
        float4 ccA = *(const float4*)(cost_sh + irow * QN + j0);
        double uiA = u_sh[irow];
        float4 ccB;
        double uiB;

        // Body macro: consumes (CCX,UIX) = row `irow`; issues guess load into
        // (CCY,UIY) at top. Sets sink >= 0 on round end.
#define POP_BODY(CCX, UIX, CCY, UIY)                                           \
        {                                                                      \
            /* top: speculative issue for the guessed next pop */              \
            const int rg_ = (have_g && krcg >= 0) ? krcg : 0;                  \
            CCY = *(const float4*)(cost_sh + rg_ * QN + j0);                   \
            UIY = u_sh[rg_];                                                   \
            /* scan current row (numpy order, strict r < d) */                 \
            const double ca0 = ((m_d + (double)CCX.x) - UIX) - v0;             \
            const double ca1 = ((m_d + (double)CCX.y) - UIX) - v1;             \
            const double ca2 = ((m_d + (double)CCX.z) - UIX) - v2;             \
            const double ca3 = ((m_d + (double)CCX.w) - UIX) - v3;             \
            const bool i0_ = !(sc & 1) && (ca0 < dv0);                         \
            const bool i1_ = !(sc & 2) && (ca1 < dv1);                         \
            const bool i2_ = !(sc & 4) && (ca2 < dv2);                         \
            const bool i3_ = !(sc & 8) && (ca3 < dv3);                         \
            const bool chkl_ = (i0_ && ca0 <= m_d) || (i1_ && ca1 <= m_d) ||   \
                               (i2_ && ca2 <= m_d) || (i3_ && ca3 <= m_d);     \
            const unsigned long long chk_ = __ballot(chkl_);                   \
            if (i0_) { dv0 = ca0; p0 = irow; }                                 \
            if (i1_) { dv1 = ca1; p1 = irow; }                                 \
            if (i2_) { dv2 = ca2; p2 = irow; }                                 \
            if (i3_) { dv3 = ca3; p3 = irow; }                                 \
            if (chk_ == 0ull && have_g) {                                      \
                /* fast commit of guessed pop */                               \
                if (krcg < 0) {                                                \
                    sink = jg;                                                 \
                } else {                                                       \
                    const int ow_ = jg >> 2, sl_ = jg & 3;                     \
                    if (lane == ow_) sc |= 1 << sl_;                           \
                    if (lane == (krcg >> 1)) {                                 \
                        if (krcg & 1) { duR1 = m_d; sr |= 2; }                 \
                        else { duR0 = m_d; sr |= 1; }                          \
                    }                                                          \
                    irow = krcg;                                               \
                }                                                              \
            } else {                                                           \
                /* slow: full argmin over sc-masked dv */                      \
                const double md0_ = (sc & 1) ? INFINITY : dv0;                 \
                const double md1_ = (sc & 2) ? INFINITY : dv1;                 \
                const double md2_ = (sc & 4) ? INFINITY : dv2;                 \
                const double md3_ = (sc & 8) ? INFINITY : dv3;                 \
                double lm_ = fmin(fmin(md0_, md1_), fmin(md2_, md3_));         \
                lm_ = fmin(lm_, dpp_mov_f64<QUAD_XOR1>(lm_));                  \
                lm_ = fmin(lm_, dpp_mov_f64<QUAD_XOR2>(lm_));                  \
                lm_ = fmin(lm_, dpp_mov_f64<ROW_ROR4>(lm_));                   \
                lm_ = fmin(lm_, dpp_mov_f64<ROW_ROR8>(lm_));                   \
                const double r0_ = read_lane_f64(lm_, 0);                      \
                const double r1_ = read_lane_f64(lm_, 16);                     \
                const double r2_ = read_lane_f64(lm_, 32);                     \
                const double r3_ = read_lane_f64(lm_, 48);                     \
                m_d = fmin(fmin(r0_, r1_), fmin(r2_, r3_));                    \
                B0 = __ballot(!(sc & 1) && (dv0 == m_d));                      \
                B1 = __ballot(!(sc & 2) && (dv1 == m_d));                      \
                B2 = __ballot(!(sc & 4) && (dv2 == m_d));                      \
                B3 = __ballot(!(sc & 8) && (dv3 == m_d));                      \
                const int jmin_ = first_tied(B0, B1, B2, B3);                  \
                const int ow_ = jmin_ >> 2, sl_ = jmin_ & 3;                   \
                const unsigned long long bit_ = 1ull << ow_;                   \
                if (sl_ == 0) B0 &= ~bit_;                                     \
                else if (sl_ == 1) B1 &= ~bit_;                                \
                else if (sl_ == 2) B2 &= ~bit_;                                \
                else B3 &= ~bit_;                                              \
                const int rsel_ = (sl_ == 0) ? rc0 : (sl_ == 1) ? rc1          \
                                 : (sl_ == 2) ? rc2 : rc3;                     \
                const int krc_ = __builtin_amdgcn_readlane(rsel_, ow_);        \
                if (krc_ < 0) {                                                \
                    sink = jmin_;                                              \
                } else {                                                       \
                    if (lane == ow_) sc |= 1 << sl_;                           \
                    if (lane == (krc_ >> 1)) {                                 \
                        if (krc_ & 1) { duR1 = m_d; sr |= 2; }                 \
                        else { duR0 = m_d; sr |= 1; }                          \
                    }                                                          \
                    irow = krc_;                                               \
                    CCY = *(const float4*)(cost_sh + irow * QN + j0);          \
                    UIY = u_sh[irow];                                          \
                }                                                              \
            }                                                                  \
            if (sink < 0) {                                                    \
                /* guess the next pop (selection only, no load) */             \
                if ((B0 | B1 | B2 | B3) != 0ull) {                             \
                    jg = first_tied(B0, B1, B2, B3);                           \
                    const int go_ = jg >> 2, gs_ = jg & 3;                     \
                    const unsigned long long gb_ = 1ull << go_;                \
                    if (gs_ == 0) B0 &= ~gb_;                                  \
                    else if (gs_ == 1) B1 &= ~gb_;                             \
                    else if (gs_ == 2) B2 &= ~gb_;                             \
                    else B3 &= ~gb_;                                           \
                    const int gr_ = (gs_ == 0) ? rc0 : (gs_ == 1) ? rc1        \
                                   : (gs_ == 2) ? rc2 : rc3;                   \
                    krcg = __builtin_amdgcn_readlane(gr_, go_);                \
                    have_g = true;                                             \
                } else {                                                       \
                    have_g = false;                                            \
                }                                                              \
            }                                                                  \
        }

        while (true) {
            POP_BODY(ccA, uiA, ccB, uiB)
            if (sink >= 0) break;
            POP_BODY(ccB, uiB, ccA, uiA)
            if (sink >= 0) break;
        }
#undef POP_BODY

        // ---- round end: dual updates (scipy _lsap_body), all registers ----
        if (sc & 1) v0 -= m_d - dv0;
        if (sc & 2) v1 -= m_d - dv1;
        if (sc & 4) v2 -= m_d - dv2;
        if (sc & 8) v3 -= m_d - dv3;
        if (sr & 1) u0 += (2 * lane == cur) ? m_d : (m_d - duR0);
        if (sr & 2) u1 += (2 * lane + 1 == cur) ? m_d : (m_d - duR1);
        u_sh[2 * lane] = u0;        // write-through for broadcast reads
        u_sh[2 * lane + 1] = u1;

        // ---- augment: all-lane uniform replay via readlanes (no LDS) ----
        int j = sink;
        while (true) {
            const int aslot = j & 3;
            const int aowner = j >> 2;
            const int psel = (aslot == 0) ? p0 : (aslot == 1) ? p1 : (aslot == 2) ? p2 : p3;
            const int pi = __builtin_amdgcn_readlane(psel, aowner);
            if (lane == aowner) {
                if (aslot == 0) rc0 = pi;
                else if (aslot == 1) rc1 = pi;
                else if (aslot == 2) rc2 = pi;
                else rc3 = pi;
            }
            const int cowner = pi >> 1;
            const int cslot = pi & 1;
            const int csel = cslot ? cr1 : cr0;
            const int nj = __builtin_amdgcn_readlane(csel, cowner);
            if (lane == cowner) {
                if (cslot) cr1 = j;
                else cr0 = j;
            }
            j = nj;
            if (pi == cur) break;
        }
    }

    // ---- epilogue: rank by col4row value (values distinct) ----
    col4row_sh[2 * lane] = cr0;
    col4row_sh[2 * lane + 1] = cr1;
    __syncthreads();
#pragma unroll
    for (int t = 0; t < 2; t++) {
        const int ii = 2 * lane + t;
        const int myv = t ? cr1 : cr0;
        int rank = 0;
        for (int t2 = 0; t2 < TN; t2++) rank += (col4row_sh[t2] < myv) ? 1 : 0;
        rows_out[b * TN + rank] = (float)myv;
        cols_out[b * TN + rank] = (float)ii;
    }
}

extern "C" void kernel_launch(void* const* d_in, const int* in_sizes, int n_in,
                              void* d_out, int out_size, void* d_ws, size_t ws_size,
                              hipStream_t stream) {
    const float* logits = (const float*)d_in[0];                  // [32,256,2048] f32
    const int* labels = (const int*)d_in[1];                      // [32,128] i32
    const unsigned char* mask_b = (const unsigned char*)d_in[2];  // [32,256] bool/i32
    const int* use_bg = (const int*)d_in[3];                      // scalar

    float* C = (float*)d_out;  // 32*256*4096
    float* rows_out = C + (size_t)BS * QN * NTGT;
    float* cols_out = rows_out + BS * TN;

    int* flag = (int*)d_ws;
    const size_t ct_off = 4096;
    const size_t ct_bytes = (size_t)BS * TN * QN * sizeof(float);  // 4 MB
    const bool useCT = ws_size >= ct_off + ct_bytes;
    float* CT = useCT ? (float*)((char*)d_ws + ct_off) : nullptr;

    detect_mask_layout<<<1, 256, 0, stream>>>(mask_b, flag);
    compute_C_kernel<<<BS * QN, 256, 0, stream>>>(logits, labels, mask_b, use_bg, flag, C, CT);
    lsa_kernel<<<BS, 64, 0, stream>>>(C, CT, rows_out, cols_out);
}